// Round 5
// baseline (765.604 us; speedup 1.0000x reference)
//
#include <hip/hip_runtime.h>
#include <hip/hip_bf16.h>
#include <hip/hip_fp16.h>
#include <float.h>

#define BB 2
#define NN 256
#define DD 64
#define KK 16
#define NH 4
#define HID 128
#define KVD 256
#define RH 64
#define NNODES (BB*NN)      // 512
#define NEDGES (NNODES*KK)  // 8192

typedef unsigned int uint32;
typedef unsigned short ushort_t;
typedef unsigned char uchar_t;

// ---- runtime dtype detection (kept from r3/r4; resolved dt=0 == fp32 on this dataset)
__device__ __forceinline__ int dtype_of(const void* ones) {
  uint32 w = *(const uint32*)ones;
  if (w == 0x3F803F80u) return 1;   // two bf16 1.0s  -> buffers are bf16
  if (w == 0x3C003C00u) return 2;   // two fp16 1.0s  -> buffers are fp16
  return 0;                          // fp32 1.0 (0x3F800000) -> buffers are fp32
}
__device__ __forceinline__ float bfbits(ushort_t s) {
  union { uint32 i; float f; } u; u.i = ((uint32)s) << 16; return u.f;
}
__device__ __forceinline__ float hfbits(ushort_t s) {
  union { ushort_t u; __half h; } c; c.u = s; return __half2float(c.h);
}
__device__ __forceinline__ float ldf(const void* p, int i, int dt) {
  if (dt == 1) return bfbits(((const ushort_t*)p)[i]);
  if (dt == 2) return hfbits(((const ushort_t*)p)[i]);
  return ((const float*)p)[i];
}
// ---- mask element width: int32 0/1 words (OR<=1) vs packed bool bytes (OR>1)
__device__ __forceinline__ int mask_is_byte(const void* m) {
  const uint32* w = (const uint32*)m;
  uint32 a = w[0] | w[1] | w[2] | w[3];
  return (a > 1u) ? 1 : 0;
}
// ---- index width: int64 has zero high-words at odd word positions
__device__ __forceinline__ int idx_is_64(const int* p) {
  return (p[1] == 0 && p[3] == 0 && p[5] == 0 && p[7] == 0) ? 1 : 0;
}

__device__ __forceinline__ float wave_sum64(float v) {
  #pragma unroll
  for (int m = 32; m; m >>= 1) v += __shfl_xor(v, m, 64);
  return v;
}
__device__ __forceinline__ float grp32_sum(float v) {
  #pragma unroll
  for (int m = 16; m; m >>= 1) v += __shfl_xor(v, m, 64);
  return v;
}

// ---------------- Kernel 1: prenorm + q/xi/xj projections (one block per node) ----
__global__ __launch_bounds__(64) void node_kernel(
    const void* __restrict__ feat, const void* __restrict__ gscale,
    const void* __restrict__ Wq, const void* __restrict__ Wxi,
    const void* __restrict__ Wxj,
    float* __restrict__ q_ws, float* __restrict__ xi_ws, float* __restrict__ xj_ws) {
  int dt = dtype_of(gscale);
  int node = blockIdx.x;
  int t = threadIdx.x;
  __shared__ float xs[DD];
  float f = ldf(feat, node * DD + t, dt);
  float ss = wave_sum64(f * f);
  float rms = sqrtf(ss) * 0.125f;           // * d^-0.5 (d=64)
  float den = fmaxf(rms, 1e-12f);
  float x = f / den * ldf(gscale, t, dt);
  xs[t] = x;
  __syncthreads();
  float q0 = 0.f, q1 = 0.f, xiv = 0.f, xjv = 0.f;
  #pragma unroll 4
  for (int d = 0; d < DD; ++d) {
    float xv = xs[d];
    q0  += xv * ldf(Wq,  d * HID + t, dt);
    q1  += xv * ldf(Wq,  d * HID + 64 + t, dt);
    xiv += xv * ldf(Wxi, d * DD + t, dt);
    xjv += xv * ldf(Wxj, d * DD + t, dt);
  }
  q_ws[node * HID + t] = q0;
  q_ws[node * HID + 64 + t] = q1;
  xi_ws[node * DD + t] = xiv;
  xj_ws[node * DD + t] = xjv;
}

// ---------------- Kernel 2: radial MLP (2 LN layers) + xe gather (one block per edge)
__global__ __launch_bounds__(64) void edge_kernel(
    const int* __restrict__ nbi, const void* __restrict__ rel,
    const void* __restrict__ W1, const void* __restrict__ b1,
    const void* __restrict__ g1, const void* __restrict__ W2,
    const void* __restrict__ b2, const void* __restrict__ g2,
    const float* __restrict__ xi_ws, const float* __restrict__ xj_ws,
    float* __restrict__ h2_ws, float* __restrict__ xe_ws) {
  int dt = dtype_of(g1);
  int i64 = idx_is_64(nbi);
  int e = blockIdx.x;
  int t = threadIdx.x;
  int node = e >> 4;
  int j = e & 15;
  int bb = node >> 8;
  __shared__ float hs[RH];
  float rd = ldf(rel, e, dt);
  float h = rd * ldf(W1, t, dt) + ldf(b1, t, dt);
  h = h / (1.f + expf(-h));                          // silu
  float mu = wave_sum64(h) * (1.f / RH);
  float c = h - mu;
  float var = wave_sum64(c * c) * (1.f / RH);
  float xn = c * rsqrtf(var + 1e-5f) * ldf(g1, t, dt);
  hs[t] = xn;
  __syncthreads();
  float p = ldf(b2, t, dt);
  #pragma unroll 4
  for (int r = 0; r < RH; ++r) p += hs[r] * ldf(W2, r * RH + t, dt);
  p = p / (1.f + expf(-p));
  mu = wave_sum64(p) * (1.f / RH);
  c = p - mu;
  var = wave_sum64(c * c) * (1.f / RH);
  float h2v = c * rsqrtf(var + 1e-5f) * ldf(g2, t, dt);
  h2_ws[e * RH + t] = h2v;
  int nb = i64 ? (int)((const long long*)nbi)[node * KK + j]
               : nbi[node * KK + j];
  xe_ws[e * DD + t] = xj_ws[(bb * NN + nb) * DD + t] + xi_ws[node * DD + t];
}

// ---------------- Kernel 3: kv[e,o] = sum_{r,d} h2[e,r]*xe[e,d]*W3[r,o*64+d] + sum_d xe*b3
// Tiled GEMM: BM=32 edges, BN=64 o, K-step = one r (64 d).  b3 folded as step r=64.
__global__ __launch_bounds__(256) void kv_kernel(
    const void* __restrict__ W3, const void* __restrict__ b3,
    const void* __restrict__ g1,
    const float* __restrict__ h2_ws, const float* __restrict__ xe_ws,
    float* __restrict__ kv_ws) {
  int dt = dtype_of(g1);
  int bx = blockIdx.x;
  int eb = bx >> 2, ob = bx & 3;
  int o0 = ob * 64;
  int tid = threadIdx.x;
  int to = tid & 15, te = tid >> 4;
  int e0 = te * 2, e1 = te * 2 + 1;   // local edge rows this thread owns
  __shared__ float xe_s[32 * 68];
  __shared__ float h2_s[32 * 68];
  __shared__ float Bs[64 * 68];
  int ebase = eb * 32;
  {
    int i0 = tid * 8;
    int el = i0 >> 6, dd = i0 & 63;
    const float4* sx = (const float4*)(xe_ws + (ebase + el) * DD + dd);
    const float4* sh = (const float4*)(h2_ws + (ebase + el) * RH + dd);
    float4 v0 = sx[0], v1 = sx[1];
    float4 w0 = sh[0], w1 = sh[1];
    float* dx = &xe_s[el * 68 + dd];
    float* dh = &h2_s[el * 68 + dd];
    *(float4*)dx = v0; *(float4*)(dx + 4) = v1;
    *(float4*)dh = w0; *(float4*)(dh + 4) = w1;
  }
  float acc[2][4] = {};
  for (int r = 0; r < 65; ++r) {
    float wv[16];
    if (dt == 0) {
      const float* src = (r < 64) ? ((const float*)W3 + r * (KVD * DD) + o0 * DD)
                                  : ((const float*)b3 + o0 * DD);
      float4 a = *(const float4*)(src + tid * 16);
      float4 b = *(const float4*)(src + tid * 16 + 4);
      float4 cc = *(const float4*)(src + tid * 16 + 8);
      float4 d = *(const float4*)(src + tid * 16 + 12);
      wv[0]=a.x; wv[1]=a.y; wv[2]=a.z; wv[3]=a.w;
      wv[4]=b.x; wv[5]=b.y; wv[6]=b.z; wv[7]=b.w;
      wv[8]=cc.x; wv[9]=cc.y; wv[10]=cc.z; wv[11]=cc.w;
      wv[12]=d.x; wv[13]=d.y; wv[14]=d.z; wv[15]=d.w;
    } else {
      const ushort_t* src = (r < 64) ? ((const ushort_t*)W3 + r * (KVD * DD) + o0 * DD)
                                     : ((const ushort_t*)b3 + o0 * DD);
      uint4 wa = *(const uint4*)(src + tid * 16);
      uint4 wb = *(const uint4*)(src + tid * 16 + 8);
      uint32 u[8] = {wa.x, wa.y, wa.z, wa.w, wb.x, wb.y, wb.z, wb.w};
      if (dt == 1) {
        #pragma unroll
        for (int c = 0; c < 8; ++c) {
          union { uint32 i; float f; } lo, hi;
          lo.i = u[c] << 16;
          hi.i = u[c] & 0xFFFF0000u;
          wv[2*c] = lo.f; wv[2*c+1] = hi.f;
        }
      } else {
        #pragma unroll
        for (int c = 0; c < 8; ++c) {
          wv[2*c]   = hfbits((ushort_t)(u[c] & 0xFFFFu));
          wv[2*c+1] = hfbits((ushort_t)(u[c] >> 16));
        }
      }
    }
    __syncthreads();   // previous iteration's Bs reads done (and iter-0: xe/h2 staged)
    {
      int ol = tid >> 2, dd = (tid & 3) * 16;
      float* dst = &Bs[ol * 68 + dd];
      #pragma unroll
      for (int c = 0; c < 16; ++c) dst[c] = wv[c];
    }
    float a0, a1;
    if (r < 64) { a0 = h2_s[e0 * 68 + r]; a1 = h2_s[e1 * 68 + r]; }
    else        { a0 = 1.f;               a1 = 1.f; }
    __syncthreads();
    #pragma unroll
    for (int d4 = 0; d4 < 16; ++d4) {
      float4 x0 = *(const float4*)&xe_s[e0 * 68 + d4 * 4];
      float4 x1 = *(const float4*)&xe_s[e1 * 68 + d4 * 4];
      float ax0[4] = {a0 * x0.x, a0 * x0.y, a0 * x0.z, a0 * x0.w};
      float ax1[4] = {a1 * x1.x, a1 * x1.y, a1 * x1.z, a1 * x1.w};
      #pragma unroll
      for (int oi = 0; oi < 4; ++oi) {
        float4 bv = *(const float4*)&Bs[(to * 4 + oi) * 68 + d4 * 4];
        acc[0][oi] += ax0[0] * bv.x + ax0[1] * bv.y + ax0[2] * bv.z + ax0[3] * bv.w;
        acc[1][oi] += ax1[0] * bv.x + ax1[1] * bv.y + ax1[2] * bv.z + ax1[3] * bv.w;
      }
    }
  }
  #pragma unroll
  for (int ei = 0; ei < 2; ++ei) {
    int e = ebase + te * 2 + ei;
    float* dst = kv_ws + e * KVD + o0 + to * 4;
    dst[0] = acc[ei][0]; dst[1] = acc[ei][1]; dst[2] = acc[ei][2]; dst[3] = acc[ei][3];
  }
}

// ---------------- Kernel 4: kv <- kv @ Wkv_out  IN PLACE  (8192x256 @ 256x256) ----
__global__ __launch_bounds__(256) void kv2_kernel(
    float* __restrict__ kv_ws, const void* __restrict__ Wkv,
    const void* __restrict__ g1) {
  int dt = dtype_of(g1);
  int eb = blockIdx.x;             // 1024 blocks, 8 edges each
  int tid = threadIdx.x;           // = output column o'
  __shared__ float kv_s[8 * 256];
  int e0 = eb * 8;
  #pragma unroll
  for (int j = 0; j < 8; ++j) kv_s[j * 256 + tid] = kv_ws[(e0 + j) * KVD + tid];
  __syncthreads();
  float acc[8] = {};
  #pragma unroll 4
  for (int kk = 0; kk < KVD; ++kk) {
    float w = ldf(Wkv, kk * KVD + tid, dt);
    #pragma unroll
    for (int j = 0; j < 8; ++j) acc[j] += kv_s[j * 256 + kk] * w;
  }
  #pragma unroll
  for (int j = 0; j < 8; ++j) kv_ws[(e0 + j) * KVD + tid] = acc[j];
}

// ---------------- Kernel 5: L2-distance attention + output projection -------------
// OUTPUT IS FP32 (reference returns jnp.float32; harness: "else float*").
__global__ __launch_bounds__(128) void attn_kernel(
    const float* __restrict__ q_ws, const float* __restrict__ kkvv_ws,
    const int* __restrict__ maskp, const void* __restrict__ Wout,
    const void* __restrict__ g1,
    float* __restrict__ out) {
  int dt = dtype_of(g1);
  int mb = mask_is_byte(maskp);
  int node = blockIdx.x;
  int t = threadIdx.x;             // 128 = H*dh
  int h = t >> 5;
  __shared__ float sim_s[NH * KK];
  __shared__ float o_s[HID];
  float qv = q_ws[node * HID + t];
  float vreg[KK];
  const float scale = 0.17677669529663689f;   // 32^-0.5
  #pragma unroll
  for (int j = 0; j < KK; ++j) {
    int e = node * KK + j;
    float kkv = kkvv_ws[e * KVD + t];
    vreg[j]   = kkvv_ws[e * KVD + HID + t];
    float diff = qv - kkv + 1e-6f;
    float s = grp32_sum(diff * diff);
    if ((t & 31) == 0) sim_s[h * KK + j] = -sqrtf(s) * scale;
  }
  __syncthreads();
  float sv[KK];
  float m = -FLT_MAX;
  #pragma unroll
  for (int j = 0; j < KK; ++j) {
    int mi = node * KK + j;
    bool msk = mb ? (((const uchar_t*)maskp)[mi] != 0) : (maskp[mi] != 0);
    float s = msk ? sim_s[h * KK + j] : -FLT_MAX;
    sv[j] = s;
    m = fmaxf(m, s);
  }
  float sum = 0.f, w[KK];
  #pragma unroll
  for (int j = 0; j < KK; ++j) { w[j] = expf(sv[j] - m); sum += w[j]; }
  float inv = 1.f / sum;
  float ot = 0.f;
  #pragma unroll
  for (int j = 0; j < KK; ++j) ot += w[j] * vreg[j];
  o_s[t] = ot * inv;
  __syncthreads();
  if (t < DD) {
    float r = 0.f;
    #pragma unroll 4
    for (int cI = 0; cI < HID; ++cI) r += o_s[cI] * ldf(Wout, cI * DD + t, dt);
    out[node * DD + t] = r;    // fp32 output
  }
}

extern "C" void kernel_launch(void* const* d_in, const int* in_sizes, int n_in,
                              void* d_out, int out_size, void* d_ws, size_t ws_size,
                              hipStream_t stream) {
  const void* feat = d_in[0];
  const int*  nbi  = (const int*)d_in[1];
  const int*  msk  = (const int*)d_in[2];
  const void* rel  = d_in[3];
  const void* gsc  = d_in[4];
  const void* Wq   = d_in[5];
  const void* Wxi  = d_in[6];
  const void* Wxj  = d_in[7];
  const void* W1   = d_in[8];
  const void* b1   = d_in[9];
  const void* g1   = d_in[10];
  const void* W2   = d_in[11];
  const void* b2   = d_in[12];
  const void* g2   = d_in[13];
  const void* W3   = d_in[14];
  const void* b3   = d_in[15];
  const void* Wkv  = d_in[16];
  const void* Wout = d_in[17];

  float* ws      = (float*)d_ws;
  float* q_ws    = ws;                          // 512*128
  float* xi_ws   = q_ws  + NNODES * HID;        // 512*64
  float* xj_ws   = xi_ws + NNODES * DD;         // 512*64
  float* h2_ws   = xj_ws + NNODES * DD;         // 8192*64
  float* xe_ws   = h2_ws + NEDGES * RH;         // 8192*64
  float* kv_ws   = xe_ws + NEDGES * DD;         // 8192*256  (transformed in place)

  node_kernel<<<NNODES, 64, 0, stream>>>(feat, gsc, Wq, Wxi, Wxj, q_ws, xi_ws, xj_ws);
  edge_kernel<<<NEDGES, 64, 0, stream>>>(nbi, rel, W1, b1, g1, W2, b2, g2,
                                         xi_ws, xj_ws, h2_ws, xe_ws);
  kv_kernel<<<1024, 256, 0, stream>>>(W3, b3, g1, h2_ws, xe_ws, kv_ws);
  kv2_kernel<<<1024, 256, 0, stream>>>(kv_ws, Wkv, g1);
  attn_kernel<<<NNODES, 128, 0, stream>>>(q_ws, kv_ws, msk, Wout, g1,
                                          (float*)d_out);
}

// Round 6
// 269.345 us; speedup vs baseline: 2.8425x; 2.8425x over previous
//
#include <hip/hip_runtime.h>
#include <hip/hip_bf16.h>
#include <float.h>

#define BB 2
#define NN 256
#define DD 64
#define KK 16
#define NH 4
#define HID 128
#define KVD 256
#define RH 64
#define NNODES (BB*NN)      // 512
#define NEDGES (NNODES*KK)  // 8192

typedef unsigned int uint32;
typedef unsigned short ushort_t;
typedef float f32x4_t __attribute__((ext_vector_type(4)));
typedef short bf16x8_t __attribute__((ext_vector_type(8)));

__device__ __forceinline__ uint32 cvtpk_bf16(float lo, float hi) {
  uint32 r;
  asm("v_cvt_pk_bf16_f32 %0, %1, %2" : "=v"(r) : "v"(lo), "v"(hi));
  return r;
}

__device__ __forceinline__ float wave_sum64(float v) {
  #pragma unroll
  for (int m = 32; m; m >>= 1) v += __shfl_xor(v, m, 64);
  return v;
}
__device__ __forceinline__ float grp32_sum(float v) {
  #pragma unroll
  for (int m = 16; m; m >>= 1) v += __shfl_xor(v, m, 64);
  return v;
}

// ---------------- Kernel 1: prenorm + q/xi/xj projections (one block per node) ----
__global__ __launch_bounds__(64) void node_kernel(
    const float* __restrict__ feat, const float* __restrict__ gscale,
    const float* __restrict__ Wq, const float* __restrict__ Wxi,
    const float* __restrict__ Wxj,
    float* __restrict__ q_ws, float* __restrict__ xi_ws, float* __restrict__ xj_ws) {
  int node = blockIdx.x;
  int t = threadIdx.x;
  __shared__ float xs[DD];
  float f = feat[node * DD + t];
  float ss = wave_sum64(f * f);
  float rms = sqrtf(ss) * 0.125f;           // * d^-0.5 (d=64)
  float den = fmaxf(rms, 1e-12f);
  float x = f / den * gscale[t];
  xs[t] = x;
  __syncthreads();
  float q0 = 0.f, q1 = 0.f, xiv = 0.f, xjv = 0.f;
  #pragma unroll 4
  for (int d = 0; d < DD; ++d) {
    float xv = xs[d];
    q0  += xv * Wq[d * HID + t];
    q1  += xv * Wq[d * HID + 64 + t];
    xiv += xv * Wxi[d * DD + t];
    xjv += xv * Wxj[d * DD + t];
  }
  q_ws[node * HID + t] = q0;
  q_ws[node * HID + 64 + t] = q1;
  xi_ws[node * DD + t] = xiv;
  xj_ws[node * DD + t] = xjv;
}

// ---------------- Kernel 2: radial MLP (2 LN layers) + xe gather (one block per edge)
__global__ __launch_bounds__(64) void edge_kernel(
    const int* __restrict__ nbi, const float* __restrict__ rel,
    const float* __restrict__ W1, const float* __restrict__ b1,
    const float* __restrict__ g1, const float* __restrict__ W2,
    const float* __restrict__ b2, const float* __restrict__ g2,
    const float* __restrict__ xi_ws, const float* __restrict__ xj_ws,
    float* __restrict__ h2_ws, float* __restrict__ xe_ws) {
  int e = blockIdx.x;
  int t = threadIdx.x;
  int node = e >> 4;
  int j = e & 15;
  int bb = node >> 8;
  __shared__ float hs[RH];
  float rd = rel[e];
  float h = rd * W1[t] + b1[t];
  h = h / (1.f + expf(-h));                          // silu
  float mu = wave_sum64(h) * (1.f / RH);
  float c = h - mu;
  float var = wave_sum64(c * c) * (1.f / RH);
  float xn = c * rsqrtf(var + 1e-5f) * g1[t];
  hs[t] = xn;
  __syncthreads();
  float p = b2[t];
  #pragma unroll 4
  for (int r = 0; r < RH; ++r) p += hs[r] * W2[r * RH + t];
  p = p / (1.f + expf(-p));
  mu = wave_sum64(p) * (1.f / RH);
  c = p - mu;
  var = wave_sum64(c * c) * (1.f / RH);
  float h2v = c * rsqrtf(var + 1e-5f) * g2[t];
  h2_ws[e * RH + t] = h2v;
  int nb = nbi[node * KK + j];
  xe_ws[e * DD + t] = xj_ws[(bb * NN + nb) * DD + t] + xi_ws[node * DD + t];
}

// ---------------- Kernel 2b: W3 (+b3 as row 64) fp32 -> bf16, layout [65][256*64] --
__global__ __launch_bounds__(256) void w3cvt_kernel(
    const float* __restrict__ W3, const float* __restrict__ b3,
    ushort_t* __restrict__ W3bf) {
  const int W3N = 64 * KVD * DD;               // 1,048,576
  int i = (blockIdx.x * 256 + threadIdx.x) * 8;  // total 65*16384 = 1,064,960
  const float* src = (i < W3N) ? (W3 + i) : (b3 + (i - W3N));
  float4 a = ((const float4*)src)[0];
  float4 b = ((const float4*)src)[1];
  float v[8] = {a.x, a.y, a.z, a.w, b.x, b.y, b.z, b.w};
  union { uint4 q; ushort_t s[8]; } o;
  #pragma unroll
  for (int jj = 0; jj < 8; ++jj) {
    uint32 u = __float_as_uint(v[jj]);
    o.s[jj] = (ushort_t)((u + 0x7FFFu + ((u >> 16) & 1u)) >> 16);  // RNE to bf16
  }
  *(uint4*)(W3bf + i) = o.q;
}

// ---------------- Kernel 3: kv via bf16 MFMA --------------------------------------
// kv[e,o] = sum_{r<=64} h2'[e,r] * sum_d xe[e,d]*W3bf[r][o*64+d]   (h2'[*,64]=1 bias)
// Block: 256 thr = 4 waves. Wave w: edges [eb*64 + w*16, +16), outs [ob*64, +64).
// A frag generated in regs: bf16(xe_f32 * h2_f32). B frags direct from global (L2).
#define LOADB(dst, rr) {                                          \
  const ushort_t* s_ = Wp + (rr) * (KVD * DD);                    \
  dst[0] = *(const bf16x8_t*)(s_);                                \
  dst[1] = *(const bf16x8_t*)(s_ + 32);                           \
  dst[2] = *(const bf16x8_t*)(s_ + 1024);                         \
  dst[3] = *(const bf16x8_t*)(s_ + 1056);                         \
  dst[4] = *(const bf16x8_t*)(s_ + 2048);                         \
  dst[5] = *(const bf16x8_t*)(s_ + 2080);                         \
  dst[6] = *(const bf16x8_t*)(s_ + 3072);                         \
  dst[7] = *(const bf16x8_t*)(s_ + 3104); }

#define AFRAG(dst, base, h) {                                     \
  union { bf16x8_t v; uint32 u[4]; } t_;                          \
  t_.u[0] = cvtpk_bf16(xf[(base)+0]*(h), xf[(base)+1]*(h));       \
  t_.u[1] = cvtpk_bf16(xf[(base)+2]*(h), xf[(base)+3]*(h));       \
  t_.u[2] = cvtpk_bf16(xf[(base)+4]*(h), xf[(base)+5]*(h));       \
  t_.u[3] = cvtpk_bf16(xf[(base)+6]*(h), xf[(base)+7]*(h));       \
  dst = t_.v; }

#define STEP(rr, bb) {                                            \
  float h2v = h2_s[e68 + (rr)];                                   \
  bf16x8_t a0_, a1_;                                              \
  AFRAG(a0_, 0, h2v); AFRAG(a1_, 8, h2v);                         \
  acc0 = __builtin_amdgcn_mfma_f32_16x16x32_bf16(a0_, bb[0], acc0, 0, 0, 0); \
  acc0 = __builtin_amdgcn_mfma_f32_16x16x32_bf16(a1_, bb[1], acc0, 0, 0, 0); \
  acc1 = __builtin_amdgcn_mfma_f32_16x16x32_bf16(a0_, bb[2], acc1, 0, 0, 0); \
  acc1 = __builtin_amdgcn_mfma_f32_16x16x32_bf16(a1_, bb[3], acc1, 0, 0, 0); \
  acc2 = __builtin_amdgcn_mfma_f32_16x16x32_bf16(a0_, bb[4], acc2, 0, 0, 0); \
  acc2 = __builtin_amdgcn_mfma_f32_16x16x32_bf16(a1_, bb[5], acc2, 0, 0, 0); \
  acc3 = __builtin_amdgcn_mfma_f32_16x16x32_bf16(a0_, bb[6], acc3, 0, 0, 0); \
  acc3 = __builtin_amdgcn_mfma_f32_16x16x32_bf16(a1_, bb[7], acc3, 0, 0, 0); }

__global__ __launch_bounds__(256) void kv_kernel(
    const ushort_t* __restrict__ W3bf,
    const float* __restrict__ h2_ws, const float* __restrict__ xe_ws,
    float* __restrict__ kv_ws) {
  int bx = blockIdx.x;
  int eb = bx >> 2, ob = bx & 3;
  int o0 = ob * 64;
  int tid = threadIdx.x;
  int w = tid >> 6, l = tid & 63;
  int l15 = l & 15, g = l >> 4;            // g in 0..3
  int ebase = eb * 64;
  __shared__ float h2_s[64 * 68];
  {  // stage h2 tile [64 edges][64 r] -> LDS stride 68 (2-way banks only)
    int row = tid >> 2, c0 = (tid & 3) * 16;
    const float* src = h2_ws + (ebase + row) * RH + c0;
    float4 v0 = ((const float4*)src)[0];
    float4 v1 = ((const float4*)src)[1];
    float4 v2 = ((const float4*)src)[2];
    float4 v3 = ((const float4*)src)[3];
    float* dst = &h2_s[row * 68 + c0];
    ((float4*)dst)[0] = v0; ((float4*)dst)[1] = v1;
    ((float4*)dst)[2] = v2; ((float4*)dst)[3] = v3;
  }
  // xe fragment (fp32) direct from global: row = wave's edge, cols g*8..+7 (+32)
  int erow = ebase + w * 16 + l15;
  const float* xsrc = xe_ws + erow * DD + g * 8;
  float xf[16];
  #pragma unroll
  for (int jj = 0; jj < 8; ++jj) xf[jj] = xsrc[jj];
  #pragma unroll
  for (int jj = 0; jj < 8; ++jj) xf[8 + jj] = xsrc[32 + jj];
  __syncthreads();

  int e68 = (w * 16 + l15) * 68;
  const ushort_t* Wp = W3bf + (size_t)(o0 + l15) * 64 + g * 8;
  f32x4_t acc0 = {0.f, 0.f, 0.f, 0.f};
  f32x4_t acc1 = {0.f, 0.f, 0.f, 0.f};
  f32x4_t acc2 = {0.f, 0.f, 0.f, 0.f};
  f32x4_t acc3 = {0.f, 0.f, 0.f, 0.f};
  bf16x8_t bA[8], bB[8];
  LOADB(bA, 0);
  for (int r = 0; r < 64; r += 2) {
    LOADB(bB, r + 1);
    STEP(r, bA);
    LOADB(bA, r + 2);        // r+2 <= 64 (row 64 = bias, loaded on last iter)
    STEP(r + 1, bB);
  }
  {  // bias step r=64: h2'=1
    bf16x8_t a0_, a1_;
    AFRAG(a0_, 0, 1.0f); AFRAG(a1_, 8, 1.0f);
    acc0 = __builtin_amdgcn_mfma_f32_16x16x32_bf16(a0_, bA[0], acc0, 0, 0, 0);
    acc0 = __builtin_amdgcn_mfma_f32_16x16x32_bf16(a1_, bA[1], acc0, 0, 0, 0);
    acc1 = __builtin_amdgcn_mfma_f32_16x16x32_bf16(a0_, bA[2], acc1, 0, 0, 0);
    acc1 = __builtin_amdgcn_mfma_f32_16x16x32_bf16(a1_, bA[3], acc1, 0, 0, 0);
    acc2 = __builtin_amdgcn_mfma_f32_16x16x32_bf16(a0_, bA[4], acc2, 0, 0, 0);
    acc2 = __builtin_amdgcn_mfma_f32_16x16x32_bf16(a1_, bA[5], acc2, 0, 0, 0);
    acc3 = __builtin_amdgcn_mfma_f32_16x16x32_bf16(a0_, bA[6], acc3, 0, 0, 0);
    acc3 = __builtin_amdgcn_mfma_f32_16x16x32_bf16(a1_, bA[7], acc3, 0, 0, 0);
  }
  // D layout (m89-verified): col = lane&15, row = (lane>>4)*4 + reg
  int orow = (ebase + w * 16 + g * 4) * KVD + o0 + l15;
  #pragma unroll
  for (int q = 0; q < 4; ++q) kv_ws[orow + q * KVD +  0] = acc0[q];
  #pragma unroll
  for (int q = 0; q < 4; ++q) kv_ws[orow + q * KVD + 16] = acc1[q];
  #pragma unroll
  for (int q = 0; q < 4; ++q) kv_ws[orow + q * KVD + 32] = acc2[q];
  #pragma unroll
  for (int q = 0; q < 4; ++q) kv_ws[orow + q * KVD + 48] = acc3[q];
}

// ---------------- Kernel 4: kv <- kv @ Wkv_out  IN PLACE  (8192x256 @ 256x256) ----
__global__ __launch_bounds__(256) void kv2_kernel(
    float* __restrict__ kv_ws, const float* __restrict__ Wkv) {
  int eb = blockIdx.x;             // 1024 blocks, 8 edges each
  int tid = threadIdx.x;           // = output column o'
  __shared__ float kv_s[8 * 256];
  int e0 = eb * 8;
  #pragma unroll
  for (int j = 0; j < 8; ++j) kv_s[j * 256 + tid] = kv_ws[(e0 + j) * KVD + tid];
  __syncthreads();
  float acc[8] = {};
  #pragma unroll 4
  for (int kk = 0; kk < KVD; ++kk) {
    float wv = Wkv[kk * KVD + tid];
    #pragma unroll
    for (int j = 0; j < 8; ++j) acc[j] += kv_s[j * 256 + kk] * wv;
  }
  #pragma unroll
  for (int j = 0; j < 8; ++j) kv_ws[(e0 + j) * KVD + tid] = acc[j];
}

// ---------------- Kernel 5: L2-distance attention + output projection (fp32 out) --
__global__ __launch_bounds__(128) void attn_kernel(
    const float* __restrict__ q_ws, const float* __restrict__ kkvv_ws,
    const int* __restrict__ maskp, const float* __restrict__ Wout,
    float* __restrict__ out) {
  int node = blockIdx.x;
  int t = threadIdx.x;             // 128 = H*dh
  int h = t >> 5;
  __shared__ float sim_s[NH * KK];
  __shared__ float o_s[HID];
  float qv = q_ws[node * HID + t];
  float vreg[KK];
  const float scale = 0.17677669529663689f;   // 32^-0.5
  #pragma unroll
  for (int j = 0; j < KK; ++j) {
    int e = node * KK + j;
    float kkv = kkvv_ws[e * KVD + t];
    vreg[j]   = kkvv_ws[e * KVD + HID + t];
    float diff = qv - kkv + 1e-6f;
    float s = grp32_sum(diff * diff);
    if ((t & 31) == 0) sim_s[h * KK + j] = -sqrtf(s) * scale;
  }
  __syncthreads();
  float sv[KK];
  float m = -FLT_MAX;
  #pragma unroll
  for (int j = 0; j < KK; ++j) {
    bool msk = maskp[node * KK + j] != 0;
    float s = msk ? sim_s[h * KK + j] : -FLT_MAX;
    sv[j] = s;
    m = fmaxf(m, s);
  }
  float sum = 0.f, wv[KK];
  #pragma unroll
  for (int j = 0; j < KK; ++j) { wv[j] = expf(sv[j] - m); sum += wv[j]; }
  float inv = 1.f / sum;
  float ot = 0.f;
  #pragma unroll
  for (int j = 0; j < KK; ++j) ot += wv[j] * vreg[j];
  o_s[t] = ot * inv;
  __syncthreads();
  if (t < DD) {
    float r = 0.f;
    #pragma unroll 4
    for (int cI = 0; cI < HID; ++cI) r += o_s[cI] * Wout[cI * DD + t];
    out[node * DD + t] = r;
  }
}

extern "C" void kernel_launch(void* const* d_in, const int* in_sizes, int n_in,
                              void* d_out, int out_size, void* d_ws, size_t ws_size,
                              hipStream_t stream) {
  const float* feat = (const float*)d_in[0];
  const int*   nbi  = (const int*)d_in[1];
  const int*   msk  = (const int*)d_in[2];
  const float* rel  = (const float*)d_in[3];
  const float* gsc  = (const float*)d_in[4];
  const float* Wq   = (const float*)d_in[5];
  const float* Wxi  = (const float*)d_in[6];
  const float* Wxj  = (const float*)d_in[7];
  const float* W1   = (const float*)d_in[8];
  const float* b1   = (const float*)d_in[9];
  const float* g1   = (const float*)d_in[10];
  const float* W2   = (const float*)d_in[11];
  const float* b2   = (const float*)d_in[12];
  const float* g2   = (const float*)d_in[13];
  const float* W3   = (const float*)d_in[14];
  const float* b3   = (const float*)d_in[15];
  const float* Wkv  = (const float*)d_in[16];
  const float* Wout = (const float*)d_in[17];

  float* ws      = (float*)d_ws;
  float* q_ws    = ws;                          // 512*128           = 65536 f
  float* xi_ws   = q_ws  + NNODES * HID;        // 512*64
  float* xj_ws   = xi_ws + NNODES * DD;         // 512*64
  float* h2_ws   = xj_ws + NNODES * DD;         // 8192*64
  float* xe_ws   = h2_ws + NEDGES * RH;         // 8192*64
  float* kv_ws   = xe_ws + NEDGES * DD;         // 8192*256 (in-place kv2)
  ushort_t* W3bf = (ushort_t*)(kv_ws + NEDGES * KVD);   // 65*16384 bf16 (~2.1 MB)

  node_kernel<<<NNODES, 64, 0, stream>>>(feat, gsc, Wq, Wxi, Wxj, q_ws, xi_ws, xj_ws);
  edge_kernel<<<NEDGES, 64, 0, stream>>>(nbi, rel, W1, b1, g1, W2, b2, g2,
                                         xi_ws, xj_ws, h2_ws, xe_ws);
  w3cvt_kernel<<<520, 256, 0, stream>>>(W3, b3, W3bf);
  kv_kernel<<<512, 256, 0, stream>>>(W3bf, h2_ws, xe_ws, kv_ws);
  kv2_kernel<<<1024, 256, 0, stream>>>(kv_ws, Wkv);
  attn_kernel<<<NNODES, 128, 0, stream>>>(q_ws, kv_ws, msk, Wout,
                                          (float*)d_out);
}

// Round 8
// 215.552 us; speedup vs baseline: 3.5518x; 1.2496x over previous
//
#include <hip/hip_runtime.h>
#include <hip/hip_bf16.h>
#include <float.h>

#define BB 2
#define NN 256
#define DD 64
#define KK 16
#define NH 4
#define HID 128
#define KVD 256
#define RH 64
#define NNODES (BB*NN)      // 512
#define NEDGES (NNODES*KK)  // 8192

typedef unsigned int uint32;
typedef unsigned short ushort_t;
typedef float f32x4_t __attribute__((ext_vector_type(4)));
typedef short bf16x8_t __attribute__((ext_vector_type(8)));

__device__ __forceinline__ uint32 cvtpk_bf16(float lo, float hi) {
  uint32 r;
  asm("v_cvt_pk_bf16_f32 %0, %1, %2" : "=v"(r) : "v"(lo), "v"(hi));
  return r;
}

__device__ __forceinline__ float wave_sum64(float v) {
  #pragma unroll
  for (int m = 32; m; m >>= 1) v += __shfl_xor(v, m, 64);
  return v;
}
__device__ __forceinline__ float grp32_sum(float v) {
  #pragma unroll
  for (int m = 16; m; m >>= 1) v += __shfl_xor(v, m, 64);
  return v;
}

// ---------------- Kernel 1: prenorm + q/xi/xj projections (one block per node) ----
__global__ __launch_bounds__(64) void node_kernel(
    const float* __restrict__ feat, const float* __restrict__ gscale,
    const float* __restrict__ Wq, const float* __restrict__ Wxi,
    const float* __restrict__ Wxj,
    float* __restrict__ q_ws, float* __restrict__ xi_ws, float* __restrict__ xj_ws) {
  int node = blockIdx.x;
  int t = threadIdx.x;
  __shared__ float xs[DD];
  float f = feat[node * DD + t];
  float ss = wave_sum64(f * f);
  float rms = sqrtf(ss) * 0.125f;           // * d^-0.5 (d=64)
  float den = fmaxf(rms, 1e-12f);
  float x = f / den * gscale[t];
  xs[t] = x;
  __syncthreads();
  float q0 = 0.f, q1 = 0.f, xiv = 0.f, xjv = 0.f;
  #pragma unroll 4
  for (int d = 0; d < DD; ++d) {
    float xv = xs[d];
    q0  += xv * Wq[d * HID + t];
    q1  += xv * Wq[d * HID + 64 + t];
    xiv += xv * Wxi[d * DD + t];
    xjv += xv * Wxj[d * DD + t];
  }
  q_ws[node * HID + t] = q0;
  q_ws[node * HID + 64 + t] = q1;
  xi_ws[node * DD + t] = xiv;
  xj_ws[node * DD + t] = xjv;
}

// ---------------- Kernel 2: radial MLP (2 LN layers) + xe gather (one block per edge)
__global__ __launch_bounds__(64) void edge_kernel(
    const int* __restrict__ nbi, const float* __restrict__ rel,
    const float* __restrict__ W1, const float* __restrict__ b1,
    const float* __restrict__ g1, const float* __restrict__ W2,
    const float* __restrict__ b2, const float* __restrict__ g2,
    const float* __restrict__ xi_ws, const float* __restrict__ xj_ws,
    float* __restrict__ h2_ws, float* __restrict__ xe_ws) {
  int e = blockIdx.x;
  int t = threadIdx.x;
  int node = e >> 4;
  int j = e & 15;
  int bb = node >> 8;
  __shared__ float hs[RH];
  float rd = rel[e];
  float h = rd * W1[t] + b1[t];
  h = h / (1.f + expf(-h));                          // silu
  float mu = wave_sum64(h) * (1.f / RH);
  float c = h - mu;
  float var = wave_sum64(c * c) * (1.f / RH);
  float xn = c * rsqrtf(var + 1e-5f) * g1[t];
  hs[t] = xn;
  __syncthreads();
  float p = b2[t];
  #pragma unroll 4
  for (int r = 0; r < RH; ++r) p += hs[r] * W2[r * RH + t];
  p = p / (1.f + expf(-p));
  mu = wave_sum64(p) * (1.f / RH);
  c = p - mu;
  var = wave_sum64(c * c) * (1.f / RH);
  float h2v = c * rsqrtf(var + 1e-5f) * g2[t];
  h2_ws[e * RH + t] = h2v;
  int nb = nbi[node * KK + j];
  xe_ws[e * DD + t] = xj_ws[(bb * NN + nb) * DD + t] + xi_ws[node * DD + t];
}

// ---------------- Kernel 2b: W3 (+b3 as row 64) fp32 -> bf16, layout [65][256*64] --
__global__ __launch_bounds__(256) void w3cvt_kernel(
    const float* __restrict__ W3, const float* __restrict__ b3,
    ushort_t* __restrict__ W3bf) {
  const int W3N = 64 * KVD * DD;               // 1,048,576
  int i = (blockIdx.x * 256 + threadIdx.x) * 8;  // total 65*16384 = 1,064,960
  const float* src = (i < W3N) ? (W3 + i) : (b3 + (i - W3N));
  float4 a = ((const float4*)src)[0];
  float4 b = ((const float4*)src)[1];
  float v[8] = {a.x, a.y, a.z, a.w, b.x, b.y, b.z, b.w};
  union { uint4 q; ushort_t s[8]; } o;
  #pragma unroll
  for (int jj = 0; jj < 8; ++jj) {
    uint32 u = __float_as_uint(v[jj]);
    o.s[jj] = (ushort_t)((u + 0x7FFFu + ((u >> 16) & 1u)) >> 16);  // RNE to bf16
  }
  *(uint4*)(W3bf + i) = o.q;
}

// ---------------- Kernel 3: kv via bf16 MFMA, M=32/wave, depth-4 B prefetch -------
// kv[e,o] = sum_{r<=64} h2'[e,r] * sum_d xe[e,d]*W3bf[r][o*64+d]   (h2'[*,64]=1 bias)
// Block: 128 thr = 2 waves. Wave w: edges [eb*64 + w*32, +32), outs [ob*64, +64).
#define LOADB(dst, rr) {                                          \
  const ushort_t* s_ = Wp + (size_t)(rr) * (KVD * DD);            \
  dst[0] = *(const bf16x8_t*)(s_);                                \
  dst[1] = *(const bf16x8_t*)(s_ + 32);                           \
  dst[2] = *(const bf16x8_t*)(s_ + 1024);                         \
  dst[3] = *(const bf16x8_t*)(s_ + 1056);                         \
  dst[4] = *(const bf16x8_t*)(s_ + 2048);                         \
  dst[5] = *(const bf16x8_t*)(s_ + 2080);                         \
  dst[6] = *(const bf16x8_t*)(s_ + 3072);                         \
  dst[7] = *(const bf16x8_t*)(s_ + 3104); }

#define AFRAG(dst, arr, base, h) {                                \
  union { bf16x8_t v; uint32 u[4]; } t_;                          \
  t_.u[0] = cvtpk_bf16(arr[(base)+0]*(h), arr[(base)+1]*(h));     \
  t_.u[1] = cvtpk_bf16(arr[(base)+2]*(h), arr[(base)+3]*(h));     \
  t_.u[2] = cvtpk_bf16(arr[(base)+4]*(h), arr[(base)+5]*(h));     \
  t_.u[3] = cvtpk_bf16(arr[(base)+6]*(h), arr[(base)+7]*(h));     \
  dst = t_.v; }

#define STEPH(hA_, hB_, bb) {                                     \
  bf16x8_t a0A, a1A, a0B, a1B;                                    \
  AFRAG(a0A, xfA, 0, hA_); AFRAG(a1A, xfA, 8, hA_);               \
  AFRAG(a0B, xfB, 0, hB_); AFRAG(a1B, xfB, 8, hB_);               \
  accA0 = __builtin_amdgcn_mfma_f32_16x16x32_bf16(a0A, bb[0], accA0, 0, 0, 0); \
  accA0 = __builtin_amdgcn_mfma_f32_16x16x32_bf16(a1A, bb[1], accA0, 0, 0, 0); \
  accA1 = __builtin_amdgcn_mfma_f32_16x16x32_bf16(a0A, bb[2], accA1, 0, 0, 0); \
  accA1 = __builtin_amdgcn_mfma_f32_16x16x32_bf16(a1A, bb[3], accA1, 0, 0, 0); \
  accA2 = __builtin_amdgcn_mfma_f32_16x16x32_bf16(a0A, bb[4], accA2, 0, 0, 0); \
  accA2 = __builtin_amdgcn_mfma_f32_16x16x32_bf16(a1A, bb[5], accA2, 0, 0, 0); \
  accA3 = __builtin_amdgcn_mfma_f32_16x16x32_bf16(a0A, bb[6], accA3, 0, 0, 0); \
  accA3 = __builtin_amdgcn_mfma_f32_16x16x32_bf16(a1A, bb[7], accA3, 0, 0, 0); \
  accB0 = __builtin_amdgcn_mfma_f32_16x16x32_bf16(a0B, bb[0], accB0, 0, 0, 0); \
  accB0 = __builtin_amdgcn_mfma_f32_16x16x32_bf16(a1B, bb[1], accB0, 0, 0, 0); \
  accB1 = __builtin_amdgcn_mfma_f32_16x16x32_bf16(a0B, bb[2], accB1, 0, 0, 0); \
  accB1 = __builtin_amdgcn_mfma_f32_16x16x32_bf16(a1B, bb[3], accB1, 0, 0, 0); \
  accB2 = __builtin_amdgcn_mfma_f32_16x16x32_bf16(a0B, bb[4], accB2, 0, 0, 0); \
  accB2 = __builtin_amdgcn_mfma_f32_16x16x32_bf16(a1B, bb[5], accB2, 0, 0, 0); \
  accB3 = __builtin_amdgcn_mfma_f32_16x16x32_bf16(a0B, bb[6], accB3, 0, 0, 0); \
  accB3 = __builtin_amdgcn_mfma_f32_16x16x32_bf16(a1B, bb[7], accB3, 0, 0, 0); }

__global__ __launch_bounds__(128) void kv_kernel(
    const ushort_t* __restrict__ W3bf,
    const float* __restrict__ h2_ws, const float* __restrict__ xe_ws,
    float* __restrict__ kv_ws) {
  int bx = blockIdx.x;
  int eb = bx >> 2, ob = bx & 3;       // 128 edge-groups x 4 col-groups
  int o0 = ob * 64;
  int tid = threadIdx.x;
  int w = tid >> 6, l = tid & 63;
  int l15 = l & 15, g = l >> 4;        // g in 0..3
  int ebase = eb * 64;
  __shared__ float h2_s[64 * 68];
  {  // stage h2 tile [64 edges][64 r] -> LDS stride 68
    int row = tid >> 1, c0 = (tid & 1) * 32;
    const float* src = h2_ws + (ebase + row) * RH + c0;
    float* dst = &h2_s[row * 68 + c0];
    #pragma unroll
    for (int q = 0; q < 8; ++q) ((float4*)dst)[q] = ((const float4*)src)[q];
  }
  // xe fragments (fp32) direct from global: two edge rows per lane
  int erowA = ebase + w * 32 + l15;
  const float* xsrcA = xe_ws + erowA * DD + g * 8;
  const float* xsrcB = xsrcA + 16 * DD;
  float xfA[16], xfB[16];
  #pragma unroll
  for (int jj = 0; jj < 8; ++jj) { xfA[jj] = xsrcA[jj]; xfA[8 + jj] = xsrcA[32 + jj]; }
  #pragma unroll
  for (int jj = 0; jj < 8; ++jj) { xfB[jj] = xsrcB[jj]; xfB[8 + jj] = xsrcB[32 + jj]; }
  __syncthreads();

  int eA68 = (w * 32 + l15) * 68;
  int eB68 = (w * 32 + 16 + l15) * 68;
  const ushort_t* Wp = W3bf + (size_t)(o0 + l15) * 64 + g * 8;
  f32x4_t accA0 = {0,0,0,0}, accA1 = {0,0,0,0}, accA2 = {0,0,0,0}, accA3 = {0,0,0,0};
  f32x4_t accB0 = {0,0,0,0}, accB1 = {0,0,0,0}, accB2 = {0,0,0,0}, accB3 = {0,0,0,0};
  bf16x8_t buf[4][8];
  float hA[4], hB[4];
  #pragma unroll
  for (int u = 0; u < 4; ++u) {
    LOADB(buf[u], u);
    hA[u] = h2_s[eA68 + u];
    hB[u] = h2_s[eB68 + u];
  }
  for (int r = 0; r < 64; r += 4) {
    #pragma unroll
    for (int u = 0; u < 4; ++u) {
      STEPH(hA[u], hB[u], buf[u]);
      int rn = r + 4 + u;
      int rc = (rn > 64) ? 64 : rn;     // clamp: row 64 = bias row
      LOADB(buf[u], rc);
      hA[u] = h2_s[eA68 + ((rn <= 67) ? rn : 67)];   // cols 64..67 = pad (unused)
      hB[u] = h2_s[eB68 + ((rn <= 67) ? rn : 67)];
    }
  }
  // bias step r=64 (all buf[u] hold row 64 now; use buf[0], h2'=1)
  STEPH(1.0f, 1.0f, buf[0]);
  // D layout (m89-verified): col = lane&15, row = (lane>>4)*4 + reg
  int orowA = (ebase + w * 32 + g * 4) * KVD + o0 + l15;
  int orowB = orowA + 16 * KVD;
  #pragma unroll
  for (int q = 0; q < 4; ++q) {
    kv_ws[orowA + q * KVD +  0] = accA0[q];
    kv_ws[orowA + q * KVD + 16] = accA1[q];
    kv_ws[orowA + q * KVD + 32] = accA2[q];
    kv_ws[orowA + q * KVD + 48] = accA3[q];
    kv_ws[orowB + q * KVD +  0] = accB0[q];
    kv_ws[orowB + q * KVD + 16] = accB1[q];
    kv_ws[orowB + q * KVD + 32] = accB2[q];
    kv_ws[orowB + q * KVD + 48] = accB3[q];
  }
}

// ---------------- Kernel 4: kv <- kv @ Wkv_out  IN PLACE  (8192x256 @ 256x256) ----
__global__ __launch_bounds__(256) void kv2_kernel(
    float* __restrict__ kv_ws, const float* __restrict__ Wkv) {
  int eb = blockIdx.x;             // 1024 blocks, 8 edges each
  int tid = threadIdx.x;           // = output column o'
  __shared__ float kv_s[8 * 256];
  int e0 = eb * 8;
  #pragma unroll
  for (int j = 0; j < 8; ++j) kv_s[j * 256 + tid] = kv_ws[(e0 + j) * KVD + tid];
  __syncthreads();
  float acc[8] = {};
  #pragma unroll 4
  for (int kk = 0; kk < KVD; ++kk) {
    float wv = Wkv[kk * KVD + tid];
    #pragma unroll
    for (int j = 0; j < 8; ++j) acc[j] += kv_s[j * 256 + kk] * wv;
  }
  #pragma unroll
  for (int j = 0; j < 8; ++j) kv_ws[(e0 + j) * KVD + tid] = acc[j];
}

// ---------------- Kernel 5: L2-distance attention + output projection (fp32 out) --
__global__ __launch_bounds__(128) void attn_kernel(
    const float* __restrict__ q_ws, const float* __restrict__ kkvv_ws,
    const int* __restrict__ maskp, const float* __restrict__ Wout,
    float* __restrict__ out) {
  int node = blockIdx.x;
  int t = threadIdx.x;             // 128 = H*dh
  int h = t >> 5;
  __shared__ float sim_s[NH * KK];
  __shared__ float o_s[HID];
  float qv = q_ws[node * HID + t];
  float vreg[KK];
  const float scale = 0.17677669529663689f;   // 32^-0.5
  #pragma unroll
  for (int j = 0; j < KK; ++j) {
    int e = node * KK + j;
    float kkv = kkvv_ws[e * KVD + t];
    vreg[j]   = kkvv_ws[e * KVD + HID + t];
    float diff = qv - kkv + 1e-6f;
    float s = grp32_sum(diff * diff);
    if ((t & 31) == 0) sim_s[h * KK + j] = -sqrtf(s) * scale;
  }
  __syncthreads();
  float sv[KK];
  float m = -FLT_MAX;
  #pragma unroll
  for (int j = 0; j < KK; ++j) {
    bool msk = maskp[node * KK + j] != 0;
    float s = msk ? sim_s[h * KK + j] : -FLT_MAX;
    sv[j] = s;
    m = fmaxf(m, s);
  }
  float sum = 0.f, wv[KK];
  #pragma unroll
  for (int j = 0; j < KK; ++j) { wv[j] = expf(sv[j] - m); sum += wv[j]; }
  float inv = 1.f / sum;
  float ot = 0.f;
  #pragma unroll
  for (int j = 0; j < KK; ++j) ot += wv[j] * vreg[j];
  o_s[t] = ot * inv;
  __syncthreads();
  if (t < DD) {
    float r = 0.f;
    #pragma unroll 4
    for (int cI = 0; cI < HID; ++cI) r += o_s[cI] * Wout[cI * DD + t];
    out[node * DD + t] = r;
  }
}

extern "C" void kernel_launch(void* const* d_in, const int* in_sizes, int n_in,
                              void* d_out, int out_size, void* d_ws, size_t ws_size,
                              hipStream_t stream) {
  const float* feat = (const float*)d_in[0];
  const int*   nbi  = (const int*)d_in[1];
  const int*   msk  = (const int*)d_in[2];
  const float* rel  = (const float*)d_in[3];
  const float* gsc  = (const float*)d_in[4];
  const float* Wq   = (const float*)d_in[5];
  const float* Wxi  = (const float*)d_in[6];
  const float* Wxj  = (const float*)d_in[7];
  const float* W1   = (const float*)d_in[8];
  const float* b1   = (const float*)d_in[9];
  const float* g1   = (const float*)d_in[10];
  const float* W2   = (const float*)d_in[11];
  const float* b2   = (const float*)d_in[12];
  const float* g2   = (const float*)d_in[13];
  const float* W3   = (const float*)d_in[14];
  const float* b3   = (const float*)d_in[15];
  const float* Wkv  = (const float*)d_in[16];
  const float* Wout = (const float*)d_in[17];

  float* ws      = (float*)d_ws;
  float* q_ws    = ws;                          // 512*128
  float* xi_ws   = q_ws  + NNODES * HID;        // 512*64
  float* xj_ws   = xi_ws + NNODES * DD;         // 512*64
  float* h2_ws   = xj_ws + NNODES * DD;         // 8192*64
  float* xe_ws   = h2_ws + NEDGES * RH;         // 8192*64
  float* kv_ws   = xe_ws + NEDGES * DD;         // 8192*256 (in-place kv2)
  ushort_t* W3bf = (ushort_t*)(kv_ws + NEDGES * KVD);   // 65*16384 bf16 (~2.1 MB)

  node_kernel<<<NNODES, 64, 0, stream>>>(feat, gsc, Wq, Wxi, Wxj, q_ws, xi_ws, xj_ws);
  edge_kernel<<<NEDGES, 64, 0, stream>>>(nbi, rel, W1, b1, g1, W2, b2, g2,
                                         xi_ws, xj_ws, h2_ws, xe_ws);
  w3cvt_kernel<<<520, 256, 0, stream>>>(W3, b3, W3bf);
  kv_kernel<<<512, 128, 0, stream>>>(W3bf, h2_ws, xe_ws, kv_ws);
  kv2_kernel<<<1024, 256, 0, stream>>>(kv_ws, Wkv);
  attn_kernel<<<NNODES, 128, 0, stream>>>(q_ws, kv_ws, msk, Wout,
                                          (float*)d_out);
}